// Round 4
// baseline (777.612 us; speedup 1.0000x reference)
//
#include <hip/hip_runtime.h>
#include <cfloat>
#include <math.h>

#define N_SAMP 32768
#define FF 8
#define HU 128
#define EE 1024
#define VV 2048
#define PP 320
#define SIGLEN 584
#define FINAL_W 9344

typedef unsigned short u16;
typedef unsigned int u32;
typedef short s16x8 __attribute__((ext_vector_type(8)));
typedef float f32x4 __attribute__((ext_vector_type(4)));

__device__ __forceinline__ u16 f2bf(float v) {
  u32 u = __float_as_uint(v);
  return (u16)((u + 0x7fffu + ((u >> 16) & 1u)) >> 16);
}
__device__ __forceinline__ float bf2f(u16 h) {
  return __uint_as_float(((u32)h) << 16);
}
// split v = hi + mid + lo (+ residual ~2^-25 |v|)
__device__ __forceinline__ void split3(float v, u16& h, u16& m, u16& l) {
  h = f2bf(v);
  float r = v - bf2f(h);
  m = f2bf(r);
  float r2 = r - bf2f(m);
  l = f2bf(r2);
}

__device__ __forceinline__ double wave_red(double v) {
#pragma unroll
  for (int off = 32; off > 0; off >>= 1) v += __shfl_xor(v, off, 64);
  return v;
}

// ---------------- prep: W limb split (blocks 0..1023) + x stats (blocks 1024..1087) --
__global__ __launch_bounds__(256) void k_prep(const float* __restrict__ W,
                                              u16* __restrict__ Hh, u16* __restrict__ Hm,
                                              u16* __restrict__ Hl,
                                              const float* __restrict__ x,
                                              double* __restrict__ xst) {
  const int b = blockIdx.x, tid = threadIdx.x;
  if (b < 1024) {
    int i = b * 256 + tid;   // exactly covers FF*2*HU*HU = 262144
    u16 h, m, l;
    split3(W[i], h, m, l);
    Hh[i] = h; Hm[i] = m; Hl[i] = l;
  } else {
    int i0 = (b - 1024) * 512 + tid;
    double v0 = (double)x[i0], v1 = (double)x[i0 + 256];
    double s1 = wave_red(v0 + v1);
    double s2 = wave_red(v0 * v0 + v1 * v1);
    __shared__ double r1[4], r2[4];
    int wave = tid >> 6, lane = tid & 63;
    if (lane == 0) { r1[wave] = s1; r2[wave] = s2; }
    __syncthreads();
    if (tid == 0) atomicAdd(&xst[0], r1[0] + r1[1] + r1[2] + r1[3]);
    if (tid == 1) atomicAdd(&xst[1], r2[0] + r2[1] + r2[2] + r2[3]);
  }
}

// ---------------- MFMA hidden-layer GEMM, bf16 3-split x 6 passes, barrier-free -----
// Y[f][m][j] = sum_k A[m,k] W[j,k] + b[j]  (row-major out), plus column stats.
// MODE 0: A[m,k] = relu(x_m * p0_k + p1_k)        (folded input-layer BN closed form)
// MODE 1: A[m,k] = relu(Y_in[f][m][k] * p0_k + p1_k), p0/p1 from stats_prev (folded fin)
//         in-place safe: block reads only rows [m0,m0+128) and writes the same rows,
//         all reads precede the epilogue stores.
template<int MODE>
__global__ __launch_bounds__(256, 2)
void k_mgemm(const float* __restrict__ Ain,        // MODE0: x[N]; MODE1: Y[F][N][HU]
             const double* __restrict__ xstats,    // MODE0
             const float* __restrict__ w_in,       // MODE0: Win [F][HU]
             const float* __restrict__ g_in,       // MODE0: gin [F][HU]
             const float* __restrict__ beta_in,    // MODE0: betain [F][HU]
             const double* __restrict__ stats_prev,// MODE1: [F*HU][2]
             const float* __restrict__ gL,         // MODE1: gh base, [f*256+j]
             const float* __restrict__ betaL,
             const u16* __restrict__ Wh_,          // bf16 limbs, layer pre-offset
             const u16* __restrict__ Wm_,
             const u16* __restrict__ Wl_,
             const float* __restrict__ bb, int bstride,
             float* __restrict__ Yout,
             double* __restrict__ stats) {
  __shared__ float p0[HU], p1[HU], biasl[HU], xl[HU];
  __shared__ float red[2][16][128];

  const int tid = threadIdx.x;
  const int f = blockIdx.y;
  const int m0 = blockIdx.x * 128;
  const int ln = tid & 15, quad = (tid >> 4) & 3, wave = tid >> 6;

  if (tid < HU) {
    biasl[tid] = bb[(size_t)f * bstride + tid];
    if (MODE == 0) {
      double mx = xstats[0] * (1.0 / 32768.0);
      double vx = xstats[1] * (1.0 / 32768.0) - mx * mx;
      if (vx < 0) vx = 0;
      float w = w_in[f * HU + tid];
      double inv = 1.0 / sqrt((double)w * (double)w * vx + 1e-5);
      float sj = (float)inv * g_in[f * HU + tid] * w;
      p0[tid] = sj;
      p1[tid] = beta_in[f * HU + tid] - (float)mx * sj;
      xl[tid] = Ain[m0 + tid];
    } else {
      int idx = f * HU + tid;
      double S1 = stats_prev[idx * 2 + 0], S2 = stats_prev[idx * 2 + 1];
      double mean = S1 * (1.0 / 32768.0);
      double var = S2 * (1.0 / 32768.0) - mean * mean;
      if (var < 0) var = 0;
      double inv = 1.0 / sqrt(var + 1e-5);
      float scv = (float)inv * gL[f * 256 + tid];
      p0[tid] = scv;
      p1[tid] = betaL[f * 256 + tid] - (float)mean * scv;
    }
  }
  __syncthreads();

  f32x4 acc[2][8];
#pragma unroll
  for (int mt = 0; mt < 2; ++mt)
#pragma unroll
    for (int u = 0; u < 8; ++u) acc[mt][u] = (f32x4){0.f, 0.f, 0.f, 0.f};

  const int mA0 = m0 + wave * 32 + ln;   // mt=0 row
  const int mA1 = mA0 + 16;              // mt=1 row
  float x0 = 0.f, x1 = 0.f;
  if (MODE == 0) { x0 = xl[wave * 32 + ln]; x1 = xl[wave * 32 + 16 + ln]; }

  const size_t fw = (size_t)f * (2 * HU * HU);
  const u16* WhF = Wh_ + fw;
  const u16* WmF = Wm_ + fw;
  const u16* WlF = Wl_ + fw;

#pragma unroll
  for (int kk = 0; kk < 128; kk += 32) {
    float p0v[8], p1v[8];
#pragma unroll
    for (int j = 0; j < 8; ++j) {
      p0v[j] = p0[kk + quad * 8 + j];
      p1v[j] = p1[kk + quad * 8 + j];
    }
    float va0[8], va1[8];
    if (MODE == 0) {
#pragma unroll
      for (int j = 0; j < 8; ++j) {
        va0[j] = fmaxf(fmaf(x0, p0v[j], p1v[j]), 0.f);
        va1[j] = fmaxf(fmaf(x1, p0v[j], p1v[j]), 0.f);
      }
    } else {
      const float* r0 = Ain + ((size_t)(f * N_SAMP) + mA0) * HU + kk + quad * 8;
      const float* r1 = Ain + ((size_t)(f * N_SAMP) + mA1) * HU + kk + quad * 8;
      float4 a0 = *(const float4*)r0;
      float4 a1 = *(const float4*)(r0 + 4);
      float4 b0 = *(const float4*)r1;
      float4 b1 = *(const float4*)(r1 + 4);
      float ra0[8] = {a0.x, a0.y, a0.z, a0.w, a1.x, a1.y, a1.z, a1.w};
      float rb0[8] = {b0.x, b0.y, b0.z, b0.w, b1.x, b1.y, b1.z, b1.w};
#pragma unroll
      for (int j = 0; j < 8; ++j) {
        va0[j] = fmaxf(fmaf(ra0[j], p0v[j], p1v[j]), 0.f);
        va1[j] = fmaxf(fmaf(rb0[j], p0v[j], p1v[j]), 0.f);
      }
    }
    s16x8 ah0, am0, al0, ah1, am1, al1;
#pragma unroll
    for (int j = 0; j < 8; ++j) {
      u16 h, m, l;
      split3(va0[j], h, m, l);
      ah0[j] = (short)h; am0[j] = (short)m; al0[j] = (short)l;
      split3(va1[j], h, m, l);
      ah1[j] = (short)h; am1[j] = (short)m; al1[j] = (short)l;
    }
#pragma unroll
    for (int u = 0; u < 8; ++u) {
      size_t off = (size_t)((u * 16 + ln) * HU + kk + quad * 8);
      s16x8 bh = *(const s16x8*)(WhF + off);
      s16x8 bm = *(const s16x8*)(WmF + off);
      s16x8 bl = *(const s16x8*)(WlF + off);
      f32x4 c0 = acc[0][u], c1 = acc[1][u];
      c0 = __builtin_amdgcn_mfma_f32_16x16x32_bf16(ah0, bh, c0, 0, 0, 0);
      c1 = __builtin_amdgcn_mfma_f32_16x16x32_bf16(ah1, bh, c1, 0, 0, 0);
      c0 = __builtin_amdgcn_mfma_f32_16x16x32_bf16(am0, bh, c0, 0, 0, 0);
      c1 = __builtin_amdgcn_mfma_f32_16x16x32_bf16(am1, bh, c1, 0, 0, 0);
      c0 = __builtin_amdgcn_mfma_f32_16x16x32_bf16(ah0, bm, c0, 0, 0, 0);
      c1 = __builtin_amdgcn_mfma_f32_16x16x32_bf16(ah1, bm, c1, 0, 0, 0);
      c0 = __builtin_amdgcn_mfma_f32_16x16x32_bf16(al0, bh, c0, 0, 0, 0);
      c1 = __builtin_amdgcn_mfma_f32_16x16x32_bf16(al1, bh, c1, 0, 0, 0);
      c0 = __builtin_amdgcn_mfma_f32_16x16x32_bf16(am0, bm, c0, 0, 0, 0);
      c1 = __builtin_amdgcn_mfma_f32_16x16x32_bf16(am1, bm, c1, 0, 0, 0);
      c0 = __builtin_amdgcn_mfma_f32_16x16x32_bf16(ah0, bl, c0, 0, 0, 0);
      c1 = __builtin_amdgcn_mfma_f32_16x16x32_bf16(ah1, bl, c1, 0, 0, 0);
      acc[0][u] = c0; acc[1][u] = c1;
    }
  }

  // ---- epilogue: bias, column stats, row-major stores Y[f][m][n] ----
  // C layout: n = u*16+ln, m = m0 + wave*32 + mt*16 + quad*4 + reg
  float cs1[8], cs2[8];
#pragma unroll
  for (int u = 0; u < 8; ++u) { cs1[u] = 0.f; cs2[u] = 0.f; }
#pragma unroll
  for (int u = 0; u < 8; ++u) {
    int n = u * 16 + ln;
    float b = biasl[n];
#pragma unroll
    for (int mt = 0; mt < 2; ++mt) {
      int mbase = m0 + wave * 32 + mt * 16 + quad * 4;
#pragma unroll
      for (int reg = 0; reg < 4; ++reg) {
        float v = acc[mt][u][reg] + b;
        cs1[u] += v;
        cs2[u] = fmaf(v, v, cs2[u]);
        Yout[((size_t)(f * N_SAMP) + mbase + reg) * HU + n] = v;
      }
    }
  }
  int wq = wave * 4 + quad;
#pragma unroll
  for (int u = 0; u < 8; ++u) {
    red[0][wq][u * 16 + ln] = cs1[u];
    red[1][wq][u * 16 + ln] = cs2[u];
  }
  __syncthreads();
  {
    int which = tid >> 7, n = tid & 127;
    float s = 0.f;
#pragma unroll
    for (int r = 0; r < 16; ++r) s += red[which][r][n];
    atomicAdd(&stats[(f * HU + n) * 2 + which], (double)s);
  }
}

// ---------------- output layer (128 -> 1) + stats, row-major Y, folded fin ----------
__global__ __launch_bounds__(256, 4) void k_outlayer(const float* __restrict__ Y,
                                                     const double* __restrict__ stats2,
                                                     const float* __restrict__ gL,
                                                     const float* __restrict__ betaL,
                                                     const float* __restrict__ Wout,
                                                     const float* __restrict__ bout,
                                                     float* __restrict__ evs_pre,
                                                     double* __restrict__ stats3) {
  __shared__ float wj[HU], scl[HU], shl[HU];
  const int tid = threadIdx.x;
  const int f = blockIdx.y;
  const int i = blockIdx.x * 256 + tid;
  if (tid < HU) {
    int idx = f * HU + tid;
    double S1 = stats2[idx * 2 + 0], S2 = stats2[idx * 2 + 1];
    double mean = S1 * (1.0 / 32768.0);
    double var = S2 * (1.0 / 32768.0) - mean * mean;
    if (var < 0) var = 0;
    double inv = 1.0 / sqrt(var + 1e-5);
    float scv = (float)inv * gL[f * 256 + 128 + tid];
    scl[tid] = scv;
    shl[tid] = betaL[f * 256 + 128 + tid] - (float)mean * scv;
    wj[tid] = Wout[f * HU + tid];
  }
  __syncthreads();
  const float4* base = (const float4*)(Y + ((size_t)(f * N_SAMP) + i) * HU);
  float acc = 0.f;
#pragma unroll
  for (int q = 0; q < 32; ++q) {
    float4 y = base[q];
    int j = q * 4;
    acc = fmaf(fmaxf(fmaf(y.x, scl[j + 0], shl[j + 0]), 0.f), wj[j + 0], acc);
    acc = fmaf(fmaxf(fmaf(y.y, scl[j + 1], shl[j + 1]), 0.f), wj[j + 1], acc);
    acc = fmaf(fmaxf(fmaf(y.z, scl[j + 2], shl[j + 2]), 0.f), wj[j + 2], acc);
    acc = fmaf(fmaxf(fmaf(y.w, scl[j + 3], shl[j + 3]), 0.f), wj[j + 3], acc);
  }
  float yo = acc + bout[f];
  evs_pre[(size_t)f * N_SAMP + i] = yo;
  double v = (double)yo;
  double s1 = wave_red(v), s2 = wave_red(v * v);
  __shared__ double r1[4], r2[4];
  int wave = tid >> 6, lane = tid & 63;
  if (lane == 0) { r1[wave] = s1; r2[wave] = s2; }
  __syncthreads();
  if (tid == 0) atomicAdd(&stats3[f * 2 + 0], r1[0] + r1[1] + r1[2] + r1[3]);
  if (tid == 1) atomicAdd(&stats3[f * 2 + 1], r2[0] + r2[1] + r2[2] + r2[3]);
}

// ---------------- einsum lfv: fv[l,f,v] = sum_e evs[f,l,e] * eig[l,e,v] -------------
__global__ __launch_bounds__(256) void k_einsum(const float* __restrict__ evs_pre,
                                                const double* __restrict__ stats3,
                                                const float* __restrict__ gout,
                                                const float* __restrict__ betaout,
                                                const float* __restrict__ eig,
                                                float* __restrict__ fv) {
  __shared__ float ev[FF * EE];
  __shared__ float sc3s[8], sh3s[8];
  const int tid = threadIdx.x;
  const int l = blockIdx.y;
  const int v0 = blockIdx.x * 256;
  if (tid < 8) {
    double S1 = stats3[tid * 2 + 0], S2 = stats3[tid * 2 + 1];
    double mean = S1 * (1.0 / 32768.0);
    double var = S2 * (1.0 / 32768.0) - mean * mean;
    if (var < 0) var = 0;
    double inv = 1.0 / sqrt(var + 1e-5);
    float scv = (float)inv * gout[tid];
    sc3s[tid] = scv;
    sh3s[tid] = betaout[tid] - (float)mean * scv;
  }
  __syncthreads();
#pragma unroll
  for (int r = 0; r < 32; ++r) {
    int q = tid + r * 256;
    int f = q >> 10, e = q & 1023;
    float y = evs_pre[(size_t)f * N_SAMP + l * EE + e];
    ev[q] = fmaxf(fmaf(y, sc3s[f], sh3s[f]), 0.f);
  }
  __syncthreads();
  const float* up = eig + (size_t)l * EE * VV + v0 + tid;
  float acc[8] = {0, 0, 0, 0, 0, 0, 0, 0};
  for (int e0 = 0; e0 < EE; e0 += 32) {
    float u[32];
#pragma unroll
    for (int t = 0; t < 32; ++t) u[t] = up[(size_t)(e0 + t) * VV];
#pragma unroll
    for (int t = 0; t < 32; ++t) {
#pragma unroll
      for (int f = 0; f < 8; ++f) acc[f] = fmaf(ev[f * EE + e0 + t], u[t], acc[f]);
    }
  }
#pragma unroll
  for (int f = 0; f < 8; ++f) fv[((size_t)(l * FF + f)) * VV + v0 + tid] = acc[f];
}

// ---------------- per-diagram: gather, project, sort, level-3 signature -------------
__global__ __launch_bounds__(256) void k_diagram(const float* __restrict__ fv,
                                                 const int* __restrict__ dgm0,
                                                 const int* __restrict__ dgm1rel,
                                                 const int* __restrict__ dgm1ext,
                                                 const float* __restrict__ Wp,
                                                 const float* __restrict__ bp,
                                                 float* __restrict__ xbuf) {
  __shared__ float vals[640];
  __shared__ float ps[7 * 512];
  __shared__ float dXl[320][8];
  const int tid = threadIdx.x;
  const int bid = blockIdx.x;
  const int row = bid >> 1;
  const int c = bid & 1;
  const float* fvr = fv + (size_t)row * VV;

  for (int k = tid; k < 640; k += 256) {
    int idx;
    if (c == 0) idx = (k < 512) ? dgm0[(size_t)row * 512 + k] : dgm1rel[(size_t)row * 129 + (640 - k)];
    else        idx = dgm1ext[(size_t)row * 640 + k];
    vals[k] = fvr[idx];
  }
  __syncthreads();
  for (int q = tid; q < 7 * 512; q += 256) {
    int s = q >> 9, p = q & 511;
    float pv = 3.402823466e+38f;
    if (p < PP) pv = fmaf(Wp[2 * s + 1], vals[2 * p + 1], fmaf(Wp[2 * s], vals[2 * p], bp[s]));
    ps[s * 512 + p] = pv;
  }
  for (int k = 2; k <= 512; k <<= 1) {
    for (int j = k >> 1; j > 0; j >>= 1) {
      __syncthreads();
      for (int q = tid; q < 1792; q += 256) {
        int s = q >> 8, ip = q & 255;
        int i = ((ip & ~(j - 1)) << 1) | (ip & (j - 1));
        int p2 = i | j;
        float a = ps[s * 512 + i], b = ps[s * 512 + p2];
        bool up = ((i & k) == 0);
        if ((a > b) == up) { ps[s * 512 + i] = b; ps[s * 512 + p2] = a; }
      }
    }
  }
  __syncthreads();
  for (int q = tid; q < 319 * 8; q += 256) {
    int p = q >> 3, d = q & 7;
    dXl[p][d] = (d == 0) ? (1.0f / 51360.0f)
                         : ps[(d - 1) * 512 + p + 1] - ps[(d - 1) * 512 + p];
  }
  __syncthreads();
  if (tid < 64) {
    const int a = tid >> 3, b = tid & 7;
    float s1a = 0.f, s2r = 0.f;
    float s3r[8] = {0, 0, 0, 0, 0, 0, 0, 0};
    for (int p = 0; p < 319; ++p) {
      float4 dlo = *(const float4*)&dXl[p][0];
      float4 dhi = *(const float4*)&dXl[p][4];
      float dxa = dXl[p][a];
      float dxb = dXl[p][b];
      float coefA = fmaf(dxa, (1.f / 3.f), s1a);
      float w = fmaf(0.5f * dxb, coefA, s2r);
      s2r = fmaf(dxb, fmaf(0.5f, dxa, s1a), s2r);
      s3r[0] = fmaf(w, dlo.x, s3r[0]);
      s3r[1] = fmaf(w, dlo.y, s3r[1]);
      s3r[2] = fmaf(w, dlo.z, s3r[2]);
      s3r[3] = fmaf(w, dlo.w, s3r[3]);
      s3r[4] = fmaf(w, dhi.x, s3r[4]);
      s3r[5] = fmaf(w, dhi.y, s3r[5]);
      s3r[6] = fmaf(w, dhi.z, s3r[6]);
      s3r[7] = fmaf(w, dhi.w, s3r[7]);
      s1a += dxa;
    }
    const int l = row >> 3, ff = row & 7;
    float* xr = xbuf + (size_t)l * FINAL_W + ff * (2 * SIGLEN) + c * SIGLEN;
    if ((tid & 7) == 0) xr[a] = s1a;
    xr[8 + tid] = s2r;
    float* s3p = xr + 72 + tid * 8;
    *(float4*)(s3p + 0) = make_float4(s3r[0], s3r[1], s3r[2], s3r[3]);
    *(float4*)(s3p + 4) = make_float4(s3r[4], s3r[5], s3r[6], s3r[7]);
  }
}

// ---------------- final 9344-dot per l (fp64) --------------------------------------
__global__ __launch_bounds__(256) void k_rowdot(const float* __restrict__ xbuf,
                                                const float* __restrict__ Wf,
                                                const float* __restrict__ bf,
                                                double* __restrict__ outpre) {
  const int tid = threadIdx.x, l = blockIdx.x;
  const float* xr = xbuf + (size_t)l * FINAL_W;
  double acc = 0.0;
  for (int k = tid; k < FINAL_W; k += 256) acc += (double)xr[k] * (double)Wf[k];
  acc = wave_red(acc);
  __shared__ double r[4];
  int wave = tid >> 6, lane = tid & 63;
  if (lane == 0) r[wave] = acc;
  __syncthreads();
  if (tid == 0) outpre[l] = r[0] + r[1] + r[2] + r[3] + (double)bf[0];
}

// ---------------- final BN over 32 samples (fp64, eps-dominated) --------------------
__global__ __launch_bounds__(64) void k_bnfin(const double* __restrict__ outpre,
                                              const float* __restrict__ g,
                                              const float* __restrict__ beta,
                                              float* __restrict__ dout) {
  int i = threadIdx.x;
  double v = (i < 32) ? outpre[i] : 0.0;
  double s1 = wave_red(v);
  double s2 = wave_red(v * v);
  double mean = s1 * (1.0 / 32.0);
  double var = s2 * (1.0 / 32.0) - mean * mean;
  if (var < 0) var = 0;
  double inv = 1.0 / sqrt(var + 1e-5);
  if (i < 32) dout[i] = (float)((v - mean) * inv * (double)g[0] + (double)beta[0]);
}

extern "C" void kernel_launch(void* const* d_in, const int* in_sizes, int n_in,
                              void* d_out, int out_size, void* d_ws, size_t ws_size,
                              hipStream_t stream) {
  const float* eig     = (const float*)d_in[0];
  const float* eigsq   = (const float*)d_in[1];
  const int*   dgm0    = (const int*)d_in[2];
  const int*   dgm1rel = (const int*)d_in[3];
  const int*   dgm1ext = (const int*)d_in[4];
  const float* Win     = (const float*)d_in[5];
  // d_in[6] = mlp_bin: cancels exactly in input-layer BN
  const float* gin     = (const float*)d_in[7];
  const float* betain  = (const float*)d_in[8];
  const float* Wh      = (const float*)d_in[9];
  const float* bh      = (const float*)d_in[10];
  const float* gh      = (const float*)d_in[11];
  const float* betah   = (const float*)d_in[12];
  const float* Wout    = (const float*)d_in[13];
  const float* bout    = (const float*)d_in[14];
  const float* gout    = (const float*)d_in[15];
  const float* betaout = (const float*)d_in[16];
  const float* Wp      = (const float*)d_in[17];
  const float* bp      = (const float*)d_in[18];
  const float* Wfin    = (const float*)d_in[19];
  const float* bfin    = (const float*)d_in[20];
  const float* gfin    = (const float*)d_in[21];
  const float* betafin = (const float*)d_in[22];

  char* ws = (char*)d_ws;
  float*  Y       = (float*)(ws);                  // 134,217,728 B : [F][N][HU] row-major
  float*  evs_pre = (float*)(ws + 134217728u);     //   1,048,576 B : [F][N]
  float*  fv      = (float*)(ws + 135266304u);     //   2,097,152 B : [L*F][V]
  float*  xbuf    = (float*)(ws + 137363456u);     //   1,196,032 B : [L][9344]
  double* stats1  = (double*)(ws + 138576384u);    // [F*HU][2]
  double* stats2  = stats1 + 2048;                 // [F*HU][2]
  double* stats3  = stats1 + 4096;                 // [F][2]
  double* xstats  = stats1 + 4112;                 // [2]
  double* outpre  = stats1 + 4114;                 // [32]
  u16*    Whh     = (u16*)(ws + 138612736u);       // [F][2][HU][HU] bf16 limbs
  u16*    Whm     = (u16*)(ws + 139137024u);
  u16*    Whl     = (u16*)(ws + 139661312u);

  // zero the atomically-accumulated stats (ws is poisoned each call)
  hipMemsetAsync(stats1, 0, 4114 * sizeof(double), stream);

  // W limb split + x stats in one launch
  k_prep<<<1088, 256, 0, stream>>>(Wh, Whh, Whm, Whl, eig, xstats);
  // hidden layer 0 (A from scalar x)
  k_mgemm<0><<<dim3(256, FF), 256, 0, stream>>>(eig, xstats, Win, gin, betain,
                                                nullptr, nullptr, nullptr,
                                                Whh, Whm, Whl,
                                                bh, 256, Y, stats1);
  // hidden layer 1 (in-place on Y), BN-1 params folded from stats1
  k_mgemm<1><<<dim3(256, FF), 256, 0, stream>>>(Y, nullptr, nullptr, nullptr, nullptr,
                                                stats1, gh, betah,
                                                Whh + HU * HU, Whm + HU * HU, Whl + HU * HU,
                                                bh + 128, 256, Y, stats2);
  // output layer (BN-2 folded from stats2)
  k_outlayer<<<dim3(128, FF), 256, 0, stream>>>(Y, stats2, gh, betah, Wout, bout,
                                                evs_pre, stats3);
  // einsum lfv (BN-3 folded from stats3)
  k_einsum<<<dim3(8, 32), 256, 0, stream>>>(evs_pre, stats3, gout, betaout, eigsq, fv);
  // diagrams: 512 = 256 rows x {Dgm0, Dgm1}
  k_diagram<<<512, 256, 0, stream>>>(fv, dgm0, dgm1rel, dgm1ext, Wp, bp, xbuf);
  // final linear + BN over L=32
  k_rowdot<<<32, 256, 0, stream>>>(xbuf, Wfin, bfin, outpre);
  k_bnfin<<<1, 64, 0, stream>>>(outpre, gfin, betafin, (float*)d_out);
}